// Round 2
// baseline (328.959 us; speedup 1.0000x reference)
//
#include <hip/hip_runtime.h>
#include <cmath>

#define TPB   128                 // threads per block (2 waves); each thread owns 4 cols
#define TH    16                  // output rows per block tile
#define WID   512
#define HEI   512
#define NIMG  64
#define NTILE (HEI / TH)          // 32
#define NBLK  (NIMG * NTILE)      // 2048
#define NROWS (TH + 6)            // 22 input rows per tile

typedef float v2f __attribute__((ext_vector_type(2)));

struct GW { float w[7]; };

struct RowBuf { float pa[12]; float ta[12]; };

__device__ __forceinline__ v2f vsplat(float s) { v2f r; r[0] = s; r[1] = s; return r; }
__device__ __forceinline__ v2f vfma(v2f a, v2f b, v2f c) { return __builtin_elementwise_fma(a, b, c); }

// Load input row gy (global y) into buffer b: cols c0-4 .. c0+7 of pred and targ,
// zero-filled outside the image (SAME zero padding).
__device__ __forceinline__ void loadrow(int gy, int m, int c0, int clm, int clp,
                                        const float* __restrict__ pb,
                                        const float* __restrict__ tb,
                                        RowBuf& b)
{
    if (gy >= 0 && gy < HEI) {
        const float* pr = pb + (size_t)gy * WID;
        const float* tr = tb + (size_t)gy * WID;
        float4 v0 = *(const float4*)(pr + clm);
        float4 v1 = *(const float4*)(pr + c0);
        float4 v2 = *(const float4*)(pr + clp);
        float4 u0 = *(const float4*)(tr + clm);
        float4 u1 = *(const float4*)(tr + c0);
        float4 u2 = *(const float4*)(tr + clp);
        if (m == 0)       { v0 = make_float4(0.f,0.f,0.f,0.f); u0 = make_float4(0.f,0.f,0.f,0.f); }
        if (m == TPB - 1) { v2 = make_float4(0.f,0.f,0.f,0.f); u2 = make_float4(0.f,0.f,0.f,0.f); }
        b.pa[0]=v0.x; b.pa[1]=v0.y; b.pa[2]=v0.z; b.pa[3]=v0.w;
        b.pa[4]=v1.x; b.pa[5]=v1.y; b.pa[6]=v1.z; b.pa[7]=v1.w;
        b.pa[8]=v2.x; b.pa[9]=v2.y; b.pa[10]=v2.z; b.pa[11]=v2.w;
        b.ta[0]=u0.x; b.ta[1]=u0.y; b.ta[2]=u0.z; b.ta[3]=u0.w;
        b.ta[4]=u1.x; b.ta[5]=u1.y; b.ta[6]=u1.z; b.ta[7]=u1.w;
        b.ta[8]=u2.x; b.ta[9]=u2.y; b.ta[10]=u2.z; b.ta[11]=u2.w;
    } else {
#pragma unroll
        for (int k = 0; k < 12; ++k) { b.pa[k] = 0.f; b.ta[k] = 0.f; }
    }
}

// One input-row stage. cur holds row (oy0-3+IY) raw values (loaded by the
// previous stage); we prefetch row IY+1 into nxt first (overlaps with compute),
// then H-blur the packed fields {A,B}={p+t,p-t}, {S,T}={(p+t)^2,(p-t)^2} into
// ring slot IY%7; from IY>=6 finish one output row (packed V-blur + SSIM).
template <int IY, bool DOLOAD>
__device__ __forceinline__ void stage(
    int oy0, int m, int c0, int clm, int clp,
    const float* __restrict__ pb, const float* __restrict__ tb,
    const float (&wt)[7],
    RowBuf& cur, RowBuf& nxt,
    v2f (&rAB)[7][4], v2f (&rST)[7][4],
    float& acc)
{
    constexpr int SL = IY % 7;

    if (DOLOAD) loadrow(oy0 - 3 + IY + 1, m, c0, clm, clp, pb, tb, nxt);

    // window value k lives at column (c0 - 3 + k); output col c uses k = c..c+6
    v2f wAB[10], wST[10];
#pragma unroll
    for (int k = 0; k < 10; ++k) {
        const float s = cur.pa[k + 1] + cur.ta[k + 1];
        const float d = cur.pa[k + 1] - cur.ta[k + 1];
        v2f w; w[0] = s; w[1] = d;
        wAB[k] = w;
        wST[k] = w * w;
    }

#pragma unroll
    for (int c = 0; c < 4; ++c) {
        v2f sAB = vsplat(wt[0]) * wAB[c];
        v2f sST = vsplat(wt[0]) * wST[c];
#pragma unroll
        for (int i = 1; i < 7; ++i) {
            const v2f wi = vsplat(wt[i]);
            sAB = vfma(wi, wAB[c + i], sAB);
            sST = vfma(wi, wST[c + i], sST);
        }
        rAB[SL][c] = sAB;
        rST[SL][c] = sST;
    }

    if constexpr (IY >= 6) {
        const float C1 = 1e-4f, C2 = 9e-4f;
#pragma unroll
        for (int c = 0; c < 4; ++c) {
            v2f vAB = vsplat(wt[0]) * rAB[(SL + 1) % 7][c];
            v2f vST = vsplat(wt[0]) * rST[(SL + 1) % 7][c];
#pragma unroll
            for (int j = 1; j < 7; ++j) {
                const int sl = (SL + 1 + j) % 7;   // compile-time
                const v2f wj = vsplat(wt[j]);
                vAB = vfma(wj, rAB[sl][c], vAB);
                vST = vfma(wj, rST[sl][c], vST);
            }
            const v2f v2 = vAB * vAB;               // {A^2, B^2}
            const float muct2 = 0.5f * (v2[0] - v2[1]);    // 2*mu_p*mu_t
            const float muss  = 0.5f * (v2[0] + v2[1]);    // mu_p^2 + mu_t^2
            const float ptb2  = 0.5f * (vST[0] - vST[1]);  // 2*blur(p*t)
            const float ssb   = 0.5f * (vST[0] + vST[1]);  // blur(p^2+t^2)
            const float num = (muct2 + C1) * (ptb2 - muct2 + C2);
            const float den = (muss + C1) * (ssb - muss + C2);
            acc += num * __builtin_amdgcn_rcpf(den);
        }
    }
}

__global__ __launch_bounds__(TPB, 2)
void ssim_main_k(const float* __restrict__ pred,
                 const float* __restrict__ targ,
                 float* __restrict__ partial,   // NBLK floats (d_ws), or null
                 float* __restrict__ outacc,    // fallback atomic accumulator
                 GW gw)
{
    const int m    = threadIdx.x;
    const int bid  = blockIdx.x;
    const int img  = bid >> 5;            // NTILE == 32
    const int tile = bid & (NTILE - 1);
    const int oy0  = tile * TH;

    const float wt[7] = { gw.w[0], gw.w[1], gw.w[2], gw.w[3], gw.w[4], gw.w[5], gw.w[6] };

    const size_t ioff = (size_t)img * (WID * HEI);
    const float* pb = pred + ioff;
    const float* tb = targ + ioff;

    const int c0  = 4 * m;
    const int clm = (m == 0) ? 0 : (c0 - 4);          // clamped (value zeroed)
    const int clp = (m == TPB - 1) ? c0 : (c0 + 4);   // clamped (value zeroed)

    v2f rAB[7][4], rST[7][4];
    RowBuf rb0, rb1;
    float acc = 0.f;

    loadrow(oy0 - 3, m, c0, clm, clp, pb, tb, rb0);

    // NROWS = 22 stages, fully unrolled; cur = rb[IY&1], nxt = rb[(IY+1)&1]
    stage< 0, true >(oy0, m, c0, clm, clp, pb, tb, wt, rb0, rb1, rAB, rST, acc);
    stage< 1, true >(oy0, m, c0, clm, clp, pb, tb, wt, rb1, rb0, rAB, rST, acc);
    stage< 2, true >(oy0, m, c0, clm, clp, pb, tb, wt, rb0, rb1, rAB, rST, acc);
    stage< 3, true >(oy0, m, c0, clm, clp, pb, tb, wt, rb1, rb0, rAB, rST, acc);
    stage< 4, true >(oy0, m, c0, clm, clp, pb, tb, wt, rb0, rb1, rAB, rST, acc);
    stage< 5, true >(oy0, m, c0, clm, clp, pb, tb, wt, rb1, rb0, rAB, rST, acc);
    stage< 6, true >(oy0, m, c0, clm, clp, pb, tb, wt, rb0, rb1, rAB, rST, acc);
    stage< 7, true >(oy0, m, c0, clm, clp, pb, tb, wt, rb1, rb0, rAB, rST, acc);
    stage< 8, true >(oy0, m, c0, clm, clp, pb, tb, wt, rb0, rb1, rAB, rST, acc);
    stage< 9, true >(oy0, m, c0, clm, clp, pb, tb, wt, rb1, rb0, rAB, rST, acc);
    stage<10, true >(oy0, m, c0, clm, clp, pb, tb, wt, rb0, rb1, rAB, rST, acc);
    stage<11, true >(oy0, m, c0, clm, clp, pb, tb, wt, rb1, rb0, rAB, rST, acc);
    stage<12, true >(oy0, m, c0, clm, clp, pb, tb, wt, rb0, rb1, rAB, rST, acc);
    stage<13, true >(oy0, m, c0, clm, clp, pb, tb, wt, rb1, rb0, rAB, rST, acc);
    stage<14, true >(oy0, m, c0, clm, clp, pb, tb, wt, rb0, rb1, rAB, rST, acc);
    stage<15, true >(oy0, m, c0, clm, clp, pb, tb, wt, rb1, rb0, rAB, rST, acc);
    stage<16, true >(oy0, m, c0, clm, clp, pb, tb, wt, rb0, rb1, rAB, rST, acc);
    stage<17, true >(oy0, m, c0, clm, clp, pb, tb, wt, rb1, rb0, rAB, rST, acc);
    stage<18, true >(oy0, m, c0, clm, clp, pb, tb, wt, rb0, rb1, rAB, rST, acc);
    stage<19, true >(oy0, m, c0, clm, clp, pb, tb, wt, rb1, rb0, rAB, rST, acc);
    stage<20, true >(oy0, m, c0, clm, clp, pb, tb, wt, rb0, rb1, rAB, rST, acc);
    stage<21, false>(oy0, m, c0, clm, clp, pb, tb, wt, rb1, rb0, rAB, rST, acc);

    // block reduction: wave shfl tree, then cross-wave via LDS
#pragma unroll
    for (int off = 32; off > 0; off >>= 1)
        acc += __shfl_down(acc, off, 64);
    __shared__ float wpart[TPB / 64];
    if ((m & 63) == 0) wpart[m >> 6] = acc;
    __syncthreads();
    if (m == 0) {
        const float tot = wpart[0] + wpart[1];
        if (partial) partial[bid] = tot;
        else atomicAdd(outacc, tot);
    }
}

__global__ void ssim_finalize_k(const float* __restrict__ partial,
                                float* __restrict__ out, int usews)
{
    const float invN = 1.0f / (float)((size_t)NIMG * WID * HEI);
    if (usews) {
        float s = 0.f;
        for (int i = threadIdx.x; i < NBLK; i += 256) s += partial[i];
#pragma unroll
        for (int off = 32; off > 0; off >>= 1) s += __shfl_down(s, off, 64);
        __shared__ float wp[4];
        if ((threadIdx.x & 63) == 0) wp[threadIdx.x >> 6] = s;
        __syncthreads();
        if (threadIdx.x == 0) out[0] = 1.0f - (wp[0] + wp[1] + wp[2] + wp[3]) * invN;
    } else {
        if (threadIdx.x == 0) out[0] = 1.0f - out[0] * invN;
    }
}

extern "C" void kernel_launch(void* const* d_in, const int* in_sizes, int n_in,
                              void* d_out, int out_size, void* d_ws, size_t ws_size,
                              hipStream_t stream)
{
    const float* pred = (const float*)d_in[0];
    const float* targ = (const float*)d_in[1];
    float* out = (float*)d_out;

    GW gw;
    {
        double g[7], s = 0.0;
        for (int i = 0; i < 7; ++i) {
            const double c = (double)(i - 3);
            g[i] = exp(-c * c / (2.0 * 1.5 * 1.5));
            s += g[i];
        }
        for (int i = 0; i < 7; ++i) gw.w[i] = (float)(g[i] / s);
    }

    const bool usews = (ws_size >= NBLK * sizeof(float));
    float* partial = usews ? (float*)d_ws : nullptr;
    if (!usews) hipMemsetAsync(d_out, 0, sizeof(float), stream);

    ssim_main_k<<<NBLK, TPB, 0, stream>>>(pred, targ, partial, out, gw);
    ssim_finalize_k<<<1, 256, 0, stream>>>(partial, out, usews ? 1 : 0);
}

// Round 3
// 268.429 us; speedup vs baseline: 1.2255x; 1.2255x over previous
//
#include <hip/hip_runtime.h>
#include <cmath>

#define TPB   128                 // threads per block (2 waves); each thread owns 4 cols
#define TH    16                  // output rows per block tile
#define WID   512
#define HEI   512
#define NIMG  64
#define NTILE (HEI / TH)          // 32
#define NBLK  (NIMG * NTILE)      // 2048
#define NROWS (TH + 6)            // 22 input rows per tile

typedef float v2f __attribute__((ext_vector_type(2)));

struct GW { float w[7]; };

struct RowBuf { float pa[12]; float ta[12]; };

__device__ __forceinline__ v2f vsplat(float s) { v2f r; r[0] = s; r[1] = s; return r; }
__device__ __forceinline__ v2f vfma(v2f a, v2f b, v2f c) { return __builtin_elementwise_fma(a, b, c); }

// Load input row gy (global y): cols c0-4 .. c0+7 of pred and targ,
// zero-filled outside the image (SAME zero padding).
__device__ __forceinline__ void loadrow(int gy, int m, int c0, int clm, int clp,
                                        const float* __restrict__ pb,
                                        const float* __restrict__ tb,
                                        RowBuf& b)
{
    if (gy >= 0 && gy < HEI) {
        const float* pr = pb + (size_t)gy * WID;
        const float* tr = tb + (size_t)gy * WID;
        float4 v0 = *(const float4*)(pr + clm);
        float4 v1 = *(const float4*)(pr + c0);
        float4 v2 = *(const float4*)(pr + clp);
        float4 u0 = *(const float4*)(tr + clm);
        float4 u1 = *(const float4*)(tr + c0);
        float4 u2 = *(const float4*)(tr + clp);
        if (m == 0)       { v0 = make_float4(0.f,0.f,0.f,0.f); u0 = make_float4(0.f,0.f,0.f,0.f); }
        if (m == TPB - 1) { v2 = make_float4(0.f,0.f,0.f,0.f); u2 = make_float4(0.f,0.f,0.f,0.f); }
        b.pa[0]=v0.x; b.pa[1]=v0.y; b.pa[2]=v0.z; b.pa[3]=v0.w;
        b.pa[4]=v1.x; b.pa[5]=v1.y; b.pa[6]=v1.z; b.pa[7]=v1.w;
        b.pa[8]=v2.x; b.pa[9]=v2.y; b.pa[10]=v2.z; b.pa[11]=v2.w;
        b.ta[0]=u0.x; b.ta[1]=u0.y; b.ta[2]=u0.z; b.ta[3]=u0.w;
        b.ta[4]=u1.x; b.ta[5]=u1.y; b.ta[6]=u1.z; b.ta[7]=u1.w;
        b.ta[8]=u2.x; b.ta[9]=u2.y; b.ta[10]=u2.z; b.ta[11]=u2.w;
    } else {
#pragma unroll
        for (int k = 0; k < 12; ++k) { b.pa[k] = 0.f; b.ta[k] = 0.f; }
    }
}

// One input-row stage: load row (oy0-3+IY), H-blur the packed fields
// {A,B}={p+t,p-t}, {S,T}={(p+t)^2,(p-t)^2} into ring slot IY%7; from IY>=6
// finish one output row (packed V-blur + SSIM) and accumulate.
template <int IY>
__device__ __forceinline__ void stage(
    int oy0, int m, int c0, int clm, int clp,
    const float* __restrict__ pb, const float* __restrict__ tb,
    const float (&wt)[7],
    v2f (&rAB)[7][4], v2f (&rST)[7][4],
    float& acc)
{
    constexpr int SL = IY % 7;

    RowBuf cur;
    loadrow(oy0 - 3 + IY, m, c0, clm, clp, pb, tb, cur);

    // window value k lives at column (c0 - 3 + k); output col c uses k = c..c+6
    v2f wAB[10], wST[10];
#pragma unroll
    for (int k = 0; k < 10; ++k) {
        const float s = cur.pa[k + 1] + cur.ta[k + 1];
        const float d = cur.pa[k + 1] - cur.ta[k + 1];
        v2f w; w[0] = s; w[1] = d;
        wAB[k] = w;
        wST[k] = w * w;
    }

#pragma unroll
    for (int c = 0; c < 4; ++c) {
        v2f sAB = vsplat(wt[0]) * wAB[c];
        v2f sST = vsplat(wt[0]) * wST[c];
#pragma unroll
        for (int i = 1; i < 7; ++i) {
            const v2f wi = vsplat(wt[i]);
            sAB = vfma(wi, wAB[c + i], sAB);
            sST = vfma(wi, wST[c + i], sST);
        }
        rAB[SL][c] = sAB;
        rST[SL][c] = sST;
    }

    if constexpr (IY >= 6) {
        const float C1 = 1e-4f, C2 = 9e-4f;
#pragma unroll
        for (int c = 0; c < 4; ++c) {
            v2f vAB = vsplat(wt[0]) * rAB[(SL + 1) % 7][c];
            v2f vST = vsplat(wt[0]) * rST[(SL + 1) % 7][c];
#pragma unroll
            for (int j = 1; j < 7; ++j) {
                const int sl = (SL + 1 + j) % 7;   // compile-time
                const v2f wj = vsplat(wt[j]);
                vAB = vfma(wj, rAB[sl][c], vAB);
                vST = vfma(wj, rST[sl][c], vST);
            }
            const v2f v2 = vAB * vAB;               // {A^2, B^2}
            const float muct2 = 0.5f * (v2[0] - v2[1]);    // 2*mu_p*mu_t
            const float muss  = 0.5f * (v2[0] + v2[1]);    // mu_p^2 + mu_t^2
            const float ptb2  = 0.5f * (vST[0] - vST[1]);  // 2*blur(p*t)
            const float ssb   = 0.5f * (vST[0] + vST[1]);  // blur(p^2+t^2)
            const float num = (muct2 + C1) * (ptb2 - muct2 + C2);
            const float den = (muss + C1) * (ssb - muss + C2);
            acc += num * __builtin_amdgcn_rcpf(den);
        }
    }
}

__global__ __launch_bounds__(TPB, 2)
void ssim_main_k(const float* __restrict__ pred,
                 const float* __restrict__ targ,
                 float* __restrict__ partial,   // NBLK floats (d_ws), or null
                 float* __restrict__ outacc,    // fallback atomic accumulator
                 GW gw)
{
    const int m    = threadIdx.x;
    const int bid  = blockIdx.x;
    const int img  = bid >> 5;            // NTILE == 32
    const int tile = bid & (NTILE - 1);
    const int oy0  = tile * TH;

    const float wt[7] = { gw.w[0], gw.w[1], gw.w[2], gw.w[3], gw.w[4], gw.w[5], gw.w[6] };

    const size_t ioff = (size_t)img * (WID * HEI);
    const float* pb = pred + ioff;
    const float* tb = targ + ioff;

    const int c0  = 4 * m;
    const int clm = (m == 0) ? 0 : (c0 - 4);          // clamped (value zeroed)
    const int clp = (m == TPB - 1) ? c0 : (c0 + 4);   // clamped (value zeroed)

    v2f rAB[7][4], rST[7][4];
    float acc = 0.f;

    // NROWS = 22 stages, fully unrolled; ring slot = IY % 7 (compile-time)
    stage< 0>(oy0, m, c0, clm, clp, pb, tb, wt, rAB, rST, acc);
    stage< 1>(oy0, m, c0, clm, clp, pb, tb, wt, rAB, rST, acc);
    stage< 2>(oy0, m, c0, clm, clp, pb, tb, wt, rAB, rST, acc);
    stage< 3>(oy0, m, c0, clm, clp, pb, tb, wt, rAB, rST, acc);
    stage< 4>(oy0, m, c0, clm, clp, pb, tb, wt, rAB, rST, acc);
    stage< 5>(oy0, m, c0, clm, clp, pb, tb, wt, rAB, rST, acc);
    stage< 6>(oy0, m, c0, clm, clp, pb, tb, wt, rAB, rST, acc);
    stage< 7>(oy0, m, c0, clm, clp, pb, tb, wt, rAB, rST, acc);
    stage< 8>(oy0, m, c0, clm, clp, pb, tb, wt, rAB, rST, acc);
    stage< 9>(oy0, m, c0, clm, clp, pb, tb, wt, rAB, rST, acc);
    stage<10>(oy0, m, c0, clm, clp, pb, tb, wt, rAB, rST, acc);
    stage<11>(oy0, m, c0, clm, clp, pb, tb, wt, rAB, rST, acc);
    stage<12>(oy0, m, c0, clm, clp, pb, tb, wt, rAB, rST, acc);
    stage<13>(oy0, m, c0, clm, clp, pb, tb, wt, rAB, rST, acc);
    stage<14>(oy0, m, c0, clm, clp, pb, tb, wt, rAB, rST, acc);
    stage<15>(oy0, m, c0, clm, clp, pb, tb, wt, rAB, rST, acc);
    stage<16>(oy0, m, c0, clm, clp, pb, tb, wt, rAB, rST, acc);
    stage<17>(oy0, m, c0, clm, clp, pb, tb, wt, rAB, rST, acc);
    stage<18>(oy0, m, c0, clm, clp, pb, tb, wt, rAB, rST, acc);
    stage<19>(oy0, m, c0, clm, clp, pb, tb, wt, rAB, rST, acc);
    stage<20>(oy0, m, c0, clm, clp, pb, tb, wt, rAB, rST, acc);
    stage<21>(oy0, m, c0, clm, clp, pb, tb, wt, rAB, rST, acc);

    // block reduction: wave shfl tree, then cross-wave via LDS
#pragma unroll
    for (int off = 32; off > 0; off >>= 1)
        acc += __shfl_down(acc, off, 64);
    __shared__ float wpart[TPB / 64];
    if ((m & 63) == 0) wpart[m >> 6] = acc;
    __syncthreads();
    if (m == 0) {
        const float tot = wpart[0] + wpart[1];
        if (partial) partial[bid] = tot;
        else atomicAdd(outacc, tot);
    }
}

__global__ void ssim_finalize_k(const float* __restrict__ partial,
                                float* __restrict__ out, int usews)
{
    const float invN = 1.0f / (float)((size_t)NIMG * WID * HEI);
    if (usews) {
        float s = 0.f;
        for (int i = threadIdx.x; i < NBLK; i += 256) s += partial[i];
#pragma unroll
        for (int off = 32; off > 0; off >>= 1) s += __shfl_down(s, off, 64);
        __shared__ float wp[4];
        if ((threadIdx.x & 63) == 0) wp[threadIdx.x >> 6] = s;
        __syncthreads();
        if (threadIdx.x == 0) out[0] = 1.0f - (wp[0] + wp[1] + wp[2] + wp[3]) * invN;
    } else {
        if (threadIdx.x == 0) out[0] = 1.0f - out[0] * invN;
    }
}

extern "C" void kernel_launch(void* const* d_in, const int* in_sizes, int n_in,
                              void* d_out, int out_size, void* d_ws, size_t ws_size,
                              hipStream_t stream)
{
    const float* pred = (const float*)d_in[0];
    const float* targ = (const float*)d_in[1];
    float* out = (float*)d_out;

    GW gw;
    {
        double g[7], s = 0.0;
        for (int i = 0; i < 7; ++i) {
            const double c = (double)(i - 3);
            g[i] = exp(-c * c / (2.0 * 1.5 * 1.5));
            s += g[i];
        }
        for (int i = 0; i < 7; ++i) gw.w[i] = (float)(g[i] / s);
    }

    const bool usews = (ws_size >= NBLK * sizeof(float));
    float* partial = usews ? (float*)d_ws : nullptr;
    if (!usews) hipMemsetAsync(d_out, 0, sizeof(float), stream);

    ssim_main_k<<<NBLK, TPB, 0, stream>>>(pred, targ, partial, out, gw);
    ssim_finalize_k<<<1, 256, 0, stream>>>(partial, out, usews ? 1 : 0);
}

// Round 4
// 77.739 us; speedup vs baseline: 4.2316x; 3.4530x over previous
//
#include <hip/hip_runtime.h>
#include <cmath>

#define TPB   128                 // threads per block (2 waves); each thread owns 4 cols
#define TH    16                  // output rows per block tile
#define WID   512
#define HEI   512
#define NIMG  64
#define NTILE (HEI / TH)          // 32
#define NBLK  (NIMG * NTILE)      // 2048

struct GW { float w[7]; };

// One input-row stage: load row gy, horizontal 7-tap blur of the 4 fields
// (a=p+t, b=p-t, a^2, b^2) into ring slot SL; when IY>=6 finish one output
// row (vertical 7-tap from ring + SSIM math) and accumulate.
// NOTE (R3 lesson): keep everything SCALAR float and reuse one wv[10] buffer
// sequentially — the v2f packed variant kept 40 floats live and spilled
// (FETCH 77->269MB, 58->268us). Register budget is the binding constraint.
template <int SL>
__device__ __forceinline__ void ssim_stage(
    int IY, int oy0, int m, int c0, int clm, int clp,
    const float* __restrict__ pb, const float* __restrict__ tb,
    const float (&wtv)[7],
    float (&rA)[7][4], float (&rB)[7][4], float (&rS)[7][4], float (&rT)[7][4],
    float& acc)
{
    const int gy = oy0 - 3 + IY;
    float pa[12], ta[12];
    if (gy >= 0 && gy < HEI) {
        const float* pr = pb + (size_t)gy * WID;
        const float* tr = tb + (size_t)gy * WID;
        float4 v0 = *(const float4*)(pr + clm);
        float4 v1 = *(const float4*)(pr + c0);
        float4 v2 = *(const float4*)(pr + clp);
        float4 u0 = *(const float4*)(tr + clm);
        float4 u1 = *(const float4*)(tr + c0);
        float4 u2 = *(const float4*)(tr + clp);
        if (m == 0)       { v0 = make_float4(0.f,0.f,0.f,0.f); u0 = make_float4(0.f,0.f,0.f,0.f); }
        if (m == TPB - 1) { v2 = make_float4(0.f,0.f,0.f,0.f); u2 = make_float4(0.f,0.f,0.f,0.f); }
        pa[0]=v0.x; pa[1]=v0.y; pa[2]=v0.z; pa[3]=v0.w;
        pa[4]=v1.x; pa[5]=v1.y; pa[6]=v1.z; pa[7]=v1.w;
        pa[8]=v2.x; pa[9]=v2.y; pa[10]=v2.z; pa[11]=v2.w;
        ta[0]=u0.x; ta[1]=u0.y; ta[2]=u0.z; ta[3]=u0.w;
        ta[4]=u1.x; ta[5]=u1.y; ta[6]=u1.z; ta[7]=u1.w;
        ta[8]=u2.x; ta[9]=u2.y; ta[10]=u2.z; ta[11]=u2.w;
    } else {
#pragma unroll
        for (int k = 0; k < 12; ++k) { pa[k] = 0.f; ta[k] = 0.f; }
    }

    // window wv[k] = value at column (c0 - 3 + k); output col c uses wv[c..c+6]
    float wv[10];

    // field A = blur(p + t)
#pragma unroll
    for (int k = 0; k < 10; ++k) wv[k] = pa[k + 1] + ta[k + 1];
#pragma unroll
    for (int c = 0; c < 4; ++c) {
        float s = 0.f;
#pragma unroll
        for (int i = 0; i < 7; ++i) s = fmaf(wtv[i], wv[c + i], s);
        rA[SL][c] = s;
    }
    // field S = blur((p + t)^2)
#pragma unroll
    for (int k = 0; k < 10; ++k) wv[k] = wv[k] * wv[k];
#pragma unroll
    for (int c = 0; c < 4; ++c) {
        float s = 0.f;
#pragma unroll
        for (int i = 0; i < 7; ++i) s = fmaf(wtv[i], wv[c + i], s);
        rS[SL][c] = s;
    }
    // field B = blur(p - t)
#pragma unroll
    for (int k = 0; k < 10; ++k) wv[k] = pa[k + 1] - ta[k + 1];
#pragma unroll
    for (int c = 0; c < 4; ++c) {
        float s = 0.f;
#pragma unroll
        for (int i = 0; i < 7; ++i) s = fmaf(wtv[i], wv[c + i], s);
        rB[SL][c] = s;
    }
    // field T = blur((p - t)^2)
#pragma unroll
    for (int k = 0; k < 10; ++k) wv[k] = wv[k] * wv[k];
#pragma unroll
    for (int c = 0; c < 4; ++c) {
        float s = 0.f;
#pragma unroll
        for (int i = 0; i < 7; ++i) s = fmaf(wtv[i], wv[c + i], s);
        rT[SL][c] = s;
    }

    if (IY >= 6) {
        const float C1 = 1e-4f, C2 = 9e-4f;
#pragma unroll
        for (int c = 0; c < 4; ++c) {
            float vA = 0.f, vB = 0.f, vS = 0.f, vT = 0.f;
#pragma unroll
            for (int j = 0; j < 7; ++j) {
                const int sl = (SL + 1 + j) % 7;   // compile-time
                vA = fmaf(wtv[j], rA[sl][c], vA);
                vB = fmaf(wtv[j], rB[sl][c], vB);
                vS = fmaf(wtv[j], rS[sl][c], vS);
                vT = fmaf(wtv[j], rT[sl][c], vT);
            }
            const float A2 = vA * vA, B2 = vB * vB;
            const float muct2 = 0.5f * (A2 - B2);   // 2*mu_p*mu_t
            const float muss  = 0.5f * (A2 + B2);   // mu_p^2 + mu_t^2
            const float ptb2  = 0.5f * (vS - vT);   // 2*blur(p*t)
            const float ssb   = 0.5f * (vS + vT);   // blur(p^2 + t^2)
            const float num = (muct2 + C1) * (ptb2 - muct2 + C2);
            const float den = (muss + C1) * (ssb - muss + C2);
            acc += num * __builtin_amdgcn_rcpf(den);
        }
    }
}

__global__ __launch_bounds__(TPB, 2)
void ssim_main_k(const float* __restrict__ pred,
                 const float* __restrict__ targ,
                 float* __restrict__ partial,   // NBLK floats (d_ws), or null
                 float* __restrict__ outacc,    // fallback atomic accumulator
                 GW gw)
{
    const int m    = threadIdx.x;
    const int bid  = blockIdx.x;
    const int img  = bid >> 5;            // NTILE == 32
    const int tile = bid & (NTILE - 1);
    const int oy0  = tile * TH;

    const float wtv[7] = { gw.w[0], gw.w[1], gw.w[2], gw.w[3], gw.w[4], gw.w[5], gw.w[6] };

    const size_t ioff = (size_t)img * (WID * HEI);
    const float* pb = pred + ioff;
    const float* tb = targ + ioff;

    const int c0  = 4 * m;
    const int clm = (m == 0) ? 0 : (c0 - 4);          // clamped (value zeroed)
    const int clp = (m == TPB - 1) ? c0 : (c0 + 4);   // clamped (value zeroed)

    float rA[7][4], rB[7][4], rS[7][4], rT[7][4];
    float acc = 0.f;

    // 22 input rows = 3*7 + 1; unroll in groups of 7 so ring slot == IY % 7 is static
    for (int it = 0; it < 3; ++it) {
        const int base = it * 7;
        ssim_stage<0>(base + 0, oy0, m, c0, clm, clp, pb, tb, wtv, rA, rB, rS, rT, acc);
        ssim_stage<1>(base + 1, oy0, m, c0, clm, clp, pb, tb, wtv, rA, rB, rS, rT, acc);
        ssim_stage<2>(base + 2, oy0, m, c0, clm, clp, pb, tb, wtv, rA, rB, rS, rT, acc);
        ssim_stage<3>(base + 3, oy0, m, c0, clm, clp, pb, tb, wtv, rA, rB, rS, rT, acc);
        ssim_stage<4>(base + 4, oy0, m, c0, clm, clp, pb, tb, wtv, rA, rB, rS, rT, acc);
        ssim_stage<5>(base + 5, oy0, m, c0, clm, clp, pb, tb, wtv, rA, rB, rS, rT, acc);
        ssim_stage<6>(base + 6, oy0, m, c0, clm, clp, pb, tb, wtv, rA, rB, rS, rT, acc);
    }
    ssim_stage<0>(21, oy0, m, c0, clm, clp, pb, tb, wtv, rA, rB, rS, rT, acc);

    // block reduction: wave shfl tree, then cross-wave via LDS
#pragma unroll
    for (int off = 32; off > 0; off >>= 1)
        acc += __shfl_down(acc, off, 64);
    __shared__ float wpart[TPB / 64];
    if ((m & 63) == 0) wpart[m >> 6] = acc;
    __syncthreads();
    if (m == 0) {
        const float tot = wpart[0] + wpart[1];
        if (partial) partial[bid] = tot;
        else atomicAdd(outacc, tot);
    }
}

__global__ void ssim_finalize_k(const float* __restrict__ partial,
                                float* __restrict__ out, int usews)
{
    const float invN = 1.0f / (float)((size_t)NIMG * WID * HEI);
    if (usews) {
        float s = 0.f;
        for (int i = threadIdx.x; i < NBLK; i += 256) s += partial[i];
#pragma unroll
        for (int off = 32; off > 0; off >>= 1) s += __shfl_down(s, off, 64);
        __shared__ float wp[4];
        if ((threadIdx.x & 63) == 0) wp[threadIdx.x >> 6] = s;
        __syncthreads();
        if (threadIdx.x == 0) out[0] = 1.0f - (wp[0] + wp[1] + wp[2] + wp[3]) * invN;
    } else {
        if (threadIdx.x == 0) out[0] = 1.0f - out[0] * invN;
    }
}

extern "C" void kernel_launch(void* const* d_in, const int* in_sizes, int n_in,
                              void* d_out, int out_size, void* d_ws, size_t ws_size,
                              hipStream_t stream)
{
    const float* pred = (const float*)d_in[0];
    const float* targ = (const float*)d_in[1];
    float* out = (float*)d_out;

    GW gw;
    {
        double g[7], s = 0.0;
        for (int i = 0; i < 7; ++i) {
            const double c = (double)(i - 3);
            g[i] = exp(-c * c / (2.0 * 1.5 * 1.5));
            s += g[i];
        }
        for (int i = 0; i < 7; ++i) gw.w[i] = (float)(g[i] / s);
    }

    const bool usews = (ws_size >= NBLK * sizeof(float));
    float* partial = usews ? (float*)d_ws : nullptr;
    if (!usews) hipMemsetAsync(d_out, 0, sizeof(float), stream);

    ssim_main_k<<<NBLK, TPB, 0, stream>>>(pred, targ, partial, out, gw);
    ssim_finalize_k<<<1, 256, 0, stream>>>(partial, out, usews ? 1 : 0);
}

// Round 6
// 52.761 us; speedup vs baseline: 6.2348x; 1.4734x over previous
//
#include <hip/hip_runtime.h>
#include <cmath>

#define TPB   128                 // threads per block (2 waves); each thread owns 4 cols
#define TH    16                  // output rows per block tile
#define WID   512
#define HEI   512
#define NIMG  64
#define NTILE (HEI / TH)          // 32
#define NBLK  (NIMG * NTILE)      // 2048

// R4 lesson: the f32 ring (112 regs) overflowed into AGPRs -> ~200 total regs
// -> 2 waves/SIMD cap -> occupancy ~17% regardless of grid size. This version
// packs the ring as f16 column-pairs (56 regs) and runs all blurs on
// v_pk_fma_f16, targeting <=128 total regs = 4 waves/SIMD.

typedef _Float16 h2 __attribute__((ext_vector_type(2)));

struct GW { unsigned int wh[7]; };   // f16 weight broadcast pairs (lo==hi), SGPR-resident

__device__ __forceinline__ h2 pkrtz(float a, float b) {
    return __builtin_bit_cast(h2, __builtin_amdgcn_cvt_pkrtz(a, b));
}
__device__ __forceinline__ h2 fma2(h2 a, h2 b, h2 c) { return __builtin_elementwise_fma(a, b, c); }

// One input-row stage: load row gy (f32), build s=p+t / d=p-t windows, pack to
// f16 col-pairs, H-blur 4 fields {A=blur(s), B=blur(d), S=blur(s^2), T=blur(d^2)}
// into ring slot SL; when IY>=6 V-blur the ring (packed fma) + SSIM (f32).
template <int SL>
__device__ __forceinline__ void ssim_stage(
    int IY, int oy0, int m, int c0, int clm, int clp,
    const float* __restrict__ pb, const float* __restrict__ tb,
    const h2 (&w2)[7],
    h2 (&ring)[7][8],
    float& acc)
{
    const int gy = oy0 - 3 + IY;
    float pa[12], ta[12];
    if (gy >= 0 && gy < HEI) {
        const float* pr = pb + (size_t)gy * WID;
        const float* tr = tb + (size_t)gy * WID;
        float4 v0 = *(const float4*)(pr + clm);
        float4 v1 = *(const float4*)(pr + c0);
        float4 v2 = *(const float4*)(pr + clp);
        float4 u0 = *(const float4*)(tr + clm);
        float4 u1 = *(const float4*)(tr + c0);
        float4 u2 = *(const float4*)(tr + clp);
        if (m == 0)       { v0 = make_float4(0.f,0.f,0.f,0.f); u0 = make_float4(0.f,0.f,0.f,0.f); }
        if (m == TPB - 1) { v2 = make_float4(0.f,0.f,0.f,0.f); u2 = make_float4(0.f,0.f,0.f,0.f); }
        pa[0]=v0.x; pa[1]=v0.y; pa[2]=v0.z; pa[3]=v0.w;
        pa[4]=v1.x; pa[5]=v1.y; pa[6]=v1.z; pa[7]=v1.w;
        pa[8]=v2.x; pa[9]=v2.y; pa[10]=v2.z; pa[11]=v2.w;
        ta[0]=u0.x; ta[1]=u0.y; ta[2]=u0.z; ta[3]=u0.w;
        ta[4]=u1.x; ta[5]=u1.y; ta[6]=u1.z; ta[7]=u1.w;
        ta[8]=u2.x; ta[9]=u2.y; ta[10]=u2.z; ta[11]=u2.w;
    } else {
#pragma unroll
        for (int k = 0; k < 12; ++k) { pa[k] = 0.f; ta[k] = 0.f; }
    }

    // window value k = column (c0 - 3 + k); output col c uses k = c..c+6
    float ws[10], wd[10];
#pragma unroll
    for (int k = 0; k < 10; ++k) {
        ws[k] = pa[k + 1] + ta[k + 1];
        wd[k] = pa[k + 1] - ta[k + 1];
    }

    h2 W[9];   // packed sliding pairs W[k] = (w[k], w[k+1]); col-pair cp uses W[2cp..2cp+6]

    // field A = blur(s)
#pragma unroll
    for (int k = 0; k < 9; ++k) W[k] = pkrtz(ws[k], ws[k + 1]);
#pragma unroll
    for (int cp = 0; cp < 2; ++cp) {
        h2 a = w2[0] * W[2 * cp];
#pragma unroll
        for (int i = 1; i < 7; ++i) a = fma2(w2[i], W[2 * cp + i], a);
        ring[SL][0 + cp] = a;
    }
    // field S = blur(s^2)
#pragma unroll
    for (int k = 0; k < 9; ++k) W[k] = W[k] * W[k];
#pragma unroll
    for (int cp = 0; cp < 2; ++cp) {
        h2 a = w2[0] * W[2 * cp];
#pragma unroll
        for (int i = 1; i < 7; ++i) a = fma2(w2[i], W[2 * cp + i], a);
        ring[SL][4 + cp] = a;
    }
    // field B = blur(d)
#pragma unroll
    for (int k = 0; k < 9; ++k) W[k] = pkrtz(wd[k], wd[k + 1]);
#pragma unroll
    for (int cp = 0; cp < 2; ++cp) {
        h2 a = w2[0] * W[2 * cp];
#pragma unroll
        for (int i = 1; i < 7; ++i) a = fma2(w2[i], W[2 * cp + i], a);
        ring[SL][2 + cp] = a;
    }
    // field T = blur(d^2)
#pragma unroll
    for (int k = 0; k < 9; ++k) W[k] = W[k] * W[k];
#pragma unroll
    for (int cp = 0; cp < 2; ++cp) {
        h2 a = w2[0] * W[2 * cp];
#pragma unroll
        for (int i = 1; i < 7; ++i) a = fma2(w2[i], W[2 * cp + i], a);
        ring[SL][6 + cp] = a;
    }

    if (IY >= 6) {
        const float C1 = 1e-4f, C2 = 9e-4f;
#pragma unroll
        for (int cp = 0; cp < 2; ++cp) {
            h2 vA = w2[0] * ring[(SL + 1) % 7][0 + cp];
            h2 vB = w2[0] * ring[(SL + 1) % 7][2 + cp];
            h2 vS = w2[0] * ring[(SL + 1) % 7][4 + cp];
            h2 vT = w2[0] * ring[(SL + 1) % 7][6 + cp];
#pragma unroll
            for (int j = 1; j < 7; ++j) {
                const int sl = (SL + 1 + j) % 7;   // compile-time
                vA = fma2(w2[j], ring[sl][0 + cp], vA);
                vB = fma2(w2[j], ring[sl][2 + cp], vB);
                vS = fma2(w2[j], ring[sl][4 + cp], vS);
                vT = fma2(w2[j], ring[sl][6 + cp], vT);
            }
#pragma unroll
            for (int e = 0; e < 2; ++e) {
                const float fA = (float)vA[e], fB = (float)vB[e];
                const float fS = (float)vS[e], fT = (float)vT[e];
                const float A2 = fA * fA, B2 = fB * fB;
                const float muct2 = 0.5f * (A2 - B2);   // 2*mu_p*mu_t
                const float muss  = 0.5f * (A2 + B2);   // mu_p^2 + mu_t^2
                const float ptb2  = 0.5f * (fS - fT);   // 2*blur(p*t)
                const float ssb   = 0.5f * (fS + fT);   // blur(p^2 + t^2)
                const float num = (muct2 + C1) * (ptb2 - muct2 + C2);
                const float den = (muss + C1) * (ssb - muss + C2);
                acc += num * __builtin_amdgcn_rcpf(den);
            }
        }
    }
}

__global__ __launch_bounds__(TPB, 4)
void ssim_main_k(const float* __restrict__ pred,
                 const float* __restrict__ targ,
                 float* __restrict__ partial,   // NBLK floats (d_ws), or null
                 float* __restrict__ outacc,    // fallback atomic accumulator
                 GW gw)
{
    const int m    = threadIdx.x;
    const int bid  = blockIdx.x;
    const int img  = bid >> 5;            // NTILE == 32
    const int tile = bid & (NTILE - 1);
    const int oy0  = tile * TH;

    h2 w2[7];
#pragma unroll
    for (int j = 0; j < 7; ++j) w2[j] = __builtin_bit_cast(h2, gw.wh[j]);

    const size_t ioff = (size_t)img * (WID * HEI);
    const float* pb = pred + ioff;
    const float* tb = targ + ioff;

    const int c0  = 4 * m;
    const int clm = (m == 0) ? 0 : (c0 - 4);          // clamped (value zeroed)
    const int clp = (m == TPB - 1) ? c0 : (c0 + 4);   // clamped (value zeroed)

    h2 ring[7][8];   // [slot][field*2 + colpair]; fields A,B,S,T
    float acc = 0.f;

    // 22 input rows = 3*7 + 1; groups of 7 so ring slot == IY % 7 is static
    for (int it = 0; it < 3; ++it) {
        const int base = it * 7;
        ssim_stage<0>(base + 0, oy0, m, c0, clm, clp, pb, tb, w2, ring, acc);
        ssim_stage<1>(base + 1, oy0, m, c0, clm, clp, pb, tb, w2, ring, acc);
        ssim_stage<2>(base + 2, oy0, m, c0, clm, clp, pb, tb, w2, ring, acc);
        ssim_stage<3>(base + 3, oy0, m, c0, clm, clp, pb, tb, w2, ring, acc);
        ssim_stage<4>(base + 4, oy0, m, c0, clm, clp, pb, tb, w2, ring, acc);
        ssim_stage<5>(base + 5, oy0, m, c0, clm, clp, pb, tb, w2, ring, acc);
        ssim_stage<6>(base + 6, oy0, m, c0, clm, clp, pb, tb, w2, ring, acc);
    }
    ssim_stage<0>(21, oy0, m, c0, clm, clp, pb, tb, w2, ring, acc);

    // block reduction: wave shfl tree, then cross-wave via LDS
#pragma unroll
    for (int off = 32; off > 0; off >>= 1)
        acc += __shfl_down(acc, off, 64);
    __shared__ float wpart[TPB / 64];
    if ((m & 63) == 0) wpart[m >> 6] = acc;
    __syncthreads();
    if (m == 0) {
        const float tot = wpart[0] + wpart[1];
        if (partial) partial[bid] = tot;
        else atomicAdd(outacc, tot);
    }
}

__global__ void ssim_finalize_k(const float* __restrict__ partial,
                                float* __restrict__ out, int usews)
{
    const float invN = 1.0f / (float)((size_t)NIMG * WID * HEI);
    if (usews) {
        float s = 0.f;
        for (int i = threadIdx.x; i < NBLK; i += 256) s += partial[i];
#pragma unroll
        for (int off = 32; off > 0; off >>= 1) s += __shfl_down(s, off, 64);
        __shared__ float wp[4];
        if ((threadIdx.x & 63) == 0) wp[threadIdx.x >> 6] = s;
        __syncthreads();
        if (threadIdx.x == 0) out[0] = 1.0f - (wp[0] + wp[1] + wp[2] + wp[3]) * invN;
    } else {
        if (threadIdx.x == 0) out[0] = 1.0f - out[0] * invN;
    }
}

// host f32 -> f16 bits, round-to-nearest-even (weights are normal, positive)
static unsigned short f32_to_f16(float f) {
    union { float f; unsigned int u; } c; c.f = f;
    const unsigned int u = c.u;
    const int exp = (int)((u >> 23) & 0xFF) - 127 + 15;
    const unsigned int man = u & 0x7FFFFFu;
    if (exp <= 0) return 0;
    unsigned int base = ((unsigned int)exp << 10) | (man >> 13);
    const unsigned int rem = man & 0x1FFFu;
    base += (rem > 0x1000u) || (rem == 0x1000u && (base & 1u));
    return (unsigned short)base;
}
static float f16_to_f32(unsigned short h) {
    const int exp = (h >> 10) & 0x1F;
    const unsigned int man = h & 0x3FFu;
    if (exp == 0) return 0.f;
    union { unsigned int u; float f; } c;
    c.u = ((unsigned int)(exp - 15 + 127) << 23) | (man << 13);
    return c.f;
}

extern "C" void kernel_launch(void* const* d_in, const int* in_sizes, int n_in,
                              void* d_out, int out_size, void* d_ws, size_t ws_size,
                              hipStream_t stream)
{
    const float* pred = (const float*)d_in[0];
    const float* targ = (const float*)d_in[1];
    float* out = (float*)d_out;

    GW gw;
    {
        double g[7], s = 0.0;
        for (int i = 0; i < 7; ++i) {
            const double c = (double)(i - 3);
            g[i] = exp(-c * c / (2.0 * 1.5 * 1.5));
            s += g[i];
        }
        unsigned short h16[7];
        for (int i = 0; i < 7; ++i) h16[i] = f32_to_f16((float)(g[i] / s));
        // renormalize so the f16 weights sum as close to 1.0 as representable:
        // set center tap = round_f16(1 - sum(others)) to kill the systematic
        // window-normalization bias.
        float so = 0.f;
        for (int i = 0; i < 7; ++i) if (i != 3) so += f16_to_f32(h16[i]);
        h16[3] = f32_to_f16(1.0f - so);
        for (int i = 0; i < 7; ++i)
            gw.wh[i] = (unsigned int)h16[i] | ((unsigned int)h16[i] << 16);
    }

    const bool usews = (ws_size >= NBLK * sizeof(float));
    float* partial = usews ? (float*)d_ws : nullptr;
    if (!usews) (void)hipMemsetAsync(d_out, 0, sizeof(float), stream);

    ssim_main_k<<<NBLK, TPB, 0, stream>>>(pred, targ, partial, out, gw);
    ssim_finalize_k<<<1, 256, 0, stream>>>(partial, out, usews ? 1 : 0);
}